// Round 6
// baseline (211.806 us; speedup 1.0000x reference)
//
#include <hip/hip_runtime.h>
#include <hip/hip_bf16.h>

// ============================================================================
// B=512, M=40, D=64. Three bilinear layers (200 outputs each):
//   out[o,d] = relu(bias[o] + sum_c W[o,c]*U[c,d]), U[(m,n),d] = x[m,d]*h[n,d]
// Per b: GEMM C[208,64] = W[208,K'] x U[K',64] bf16. K' uses n padded to
// NPAD=104 for layers 2/3 (K'=4160, pad cols of h are zero) so every 8-slot
// MFMA fragment has constant m and 8-aligned n0 -> each consuming lane builds
// its B-fragment IN REGISTERS from x (1 f32 LDS read) and h (2 ds_read_b64),
// with NO U staging in LDS and NO build/consume barriers.
// Block = 2 b's, 512 thr = 8 waves: gm=wv>>2 (m-tiles 0-6 / 7-12), wn=(wv>>1)&1
// (which b), nh=wv&1 (nj pair: cols 32nh..32nh+31). s_barrier every 2 ksteps
// only to bound skew (L1 dedupe of twin A-frag loads); no waitcnt drains.
// ============================================================================

typedef float f32x4 __attribute__((ext_vector_type(4)));
typedef short bf16x8 __attribute__((ext_vector_type(8)));
typedef unsigned int uint;

#define XF_STR 41    // f32 x rows: 164B stride; 41*lr mod 32 covers 16 banks
#define XB_STR 44    // bf16 x rows: 88B stride (22 dw; 22*lr: 16 distinct evens)
#define HS_STR 108   // bf16 h rows: 216B stride (54 dw; same spread)

struct LDSState {
    float          xf[2][64][XF_STR];     // [bb][d][m] f32     20992 B
    __hip_bfloat16 xb[2][64][XB_STR];     // [bb][d][m] bf16    11264 B
    __hip_bfloat16 hs[2][2][64][HS_STR];  // [pp][bb][d][n]     55296 B
    float          psum[2][2][208];       // [layer&1][bb][o]    6656 B
};

static __device__ __forceinline__ float bflo(uint u) {
    uint v = u << 16; return __builtin_bit_cast(float, v);
}
static __device__ __forceinline__ float bfhi(uint u) {
    uint v = u & 0xffff0000u; return __builtin_bit_cast(float, v);
}
static __device__ __forceinline__ uint pk_bf16(float a, float b) {
    uint r; asm("v_cvt_pk_bf16_f32 %0, %1, %2" : "=v"(r) : "v"(a), "v"(b));
    return r;
}

template<int NPAD, int NK, int HASH, int ROWLO, int ROWOFF, int HSTRIDE, int A>
__device__ __forceinline__ void layer_core(
    LDSState* L, const bf16x8* __restrict__ wpk, const float* __restrict__ bias,
    const __hip_bfloat16* __restrict__ hbase, const float* __restrict__ xfbase,
    int dstpp, int lp, float* __restrict__ outb, int tid, int mt0)
{
    const int lane = tid & 63;
    const int wv = tid >> 6;
    const int wn = (wv >> 1) & 1, nh = wv & 1;
    const int q = lane >> 4, lr = lane & 15;
    const int d0 = 32 * nh + lr, d1 = d0 + 16;

    const __hip_bfloat16* hA = hbase + d0 * HSTRIDE;
    const __hip_bfloat16* hB = hbase + d1 * HSTRIDE;
    const float* xA = xfbase + d0 * XF_STR;
    const float* xB = xfbase + d1 * XF_STR;

    // per-lane fragment k-base: c0 = s*32 + 8q -> m0 = c0/NPAD, n0 = c0%NPAD
    int m0 = 0, n0 = 8 * q;          // s=0: 8q < 32 <= NPAD

    f32x4 acc[A][2];
    #pragma unroll
    for (int mi = 0; mi < A; ++mi) {
        acc[mi][0] = {0.f, 0.f, 0.f, 0.f};
        acc[mi][1] = {0.f, 0.f, 0.f, 0.f};
    }

    const bf16x8* pw = wpk + (size_t)mt0 * NK * 64 + lane;

    bf16x8 fA[A], fB[A];
    #pragma unroll
    for (int mi = 0; mi < A; ++mi) {
        fA[mi] = pw[(size_t)mi * NK * 64];
        fB[mi] = pw[(size_t)mi * NK * 64 + 64];
    }

    auto body = [&](bf16x8* f) {
        uint2 a0 = *(const uint2*)(hA + n0);
        uint2 a1 = *(const uint2*)(hA + n0 + 4);
        uint2 b0 = *(const uint2*)(hB + n0);
        uint2 b1 = *(const uint2*)(hB + n0 + 4);
        float xa = xA[m0];
        float xb = xB[m0];
        union { uint u[4]; bf16x8 v; } pa, pb;
        pa.u[0] = pk_bf16(xa * bflo(a0.x), xa * bfhi(a0.x));
        pa.u[1] = pk_bf16(xa * bflo(a0.y), xa * bfhi(a0.y));
        pa.u[2] = pk_bf16(xa * bflo(a1.x), xa * bfhi(a1.x));
        pa.u[3] = pk_bf16(xa * bflo(a1.y), xa * bfhi(a1.y));
        pb.u[0] = pk_bf16(xb * bflo(b0.x), xb * bfhi(b0.x));
        pb.u[1] = pk_bf16(xb * bflo(b0.y), xb * bfhi(b0.y));
        pb.u[2] = pk_bf16(xb * bflo(b1.x), xb * bfhi(b1.x));
        pb.u[3] = pk_bf16(xb * bflo(b1.y), xb * bfhi(b1.y));
        #pragma unroll
        for (int mi = 0; mi < A; ++mi) {
            acc[mi][0] = __builtin_amdgcn_mfma_f32_16x16x32_bf16(
                f[mi], pa.v, acc[mi][0], 0, 0, 0);
            acc[mi][1] = __builtin_amdgcn_mfma_f32_16x16x32_bf16(
                f[mi], pb.v, acc[mi][1], 0, 0, 0);
        }
        n0 += 32;
        if (n0 >= NPAD) { n0 -= NPAD; ++m0; }   // cndmask, branchless
    };

    #pragma unroll 1
    for (int s = 0; s < NK; s += 2) {           // NK is even (50 / 130)
        body(fA);
        if (s + 2 < NK) {
            #pragma unroll
            for (int mi = 0; mi < A; ++mi)
                fA[mi] = pw[(size_t)mi * NK * 64 + (size_t)(s + 2) * 64];
        }
        body(fB);
        if (s + 3 < NK) {
            #pragma unroll
            for (int mi = 0; mi < A; ++mi)
                fB[mi] = pw[(size_t)mi * NK * 64 + (size_t)(s + 3) * 64];
        }
        __builtin_amdgcn_s_barrier();           // skew bound only; no waitcnt
    }

    // ---- epilogue: C/D layout row = 4q+reg, col = lr (m89-verified) ----
    // pass 1: hidden stores + psum halves (nh==0)
    #pragma unroll
    for (int mi = 0; mi < A; ++mi) {
        const int ob = 16 * (mt0 + mi) + 4 * q;
        #pragma unroll
        for (int reg = 0; reg < 4; ++reg) {
            const int o = ob + reg;
            if (o < 200) {
                const float bs = bias[o];
                float r0 = fmaxf(acc[mi][0][reg] + bs, 0.f);
                float r1 = fmaxf(acc[mi][1][reg] + bs, 0.f);
                if (HASH && o < 100) {
                    L->hs[dstpp][wn][d0][o] = __float2bfloat16(r0);
                    L->hs[dstpp][wn][d1][o] = __float2bfloat16(r1);
                }
                if (nh == 0 && o >= ROWLO) {
                    float sv = r0 + r1;
                    sv += __shfl_xor(sv, 1, 64);
                    sv += __shfl_xor(sv, 2, 64);
                    sv += __shfl_xor(sv, 4, 64);
                    sv += __shfl_xor(sv, 8, 64);
                    if (lr == 0) L->psum[lp][wn][o] = sv;
                }
            }
        }
    }
    __syncthreads();
    // pass 2: nh==1 combines and stores to global (overlaps next layer)
    if (nh == 1) {
        #pragma unroll
        for (int mi = 0; mi < A; ++mi) {
            const int ob = 16 * (mt0 + mi) + 4 * q;
            #pragma unroll
            for (int reg = 0; reg < 4; ++reg) {
                const int o = ob + reg;
                if (o < 200 && o >= ROWLO) {
                    const float bs = bias[o];
                    float r0 = fmaxf(acc[mi][0][reg] + bs, 0.f);
                    float r1 = fmaxf(acc[mi][1][reg] + bs, 0.f);
                    float sv = r0 + r1;
                    sv += __shfl_xor(sv, 1, 64);
                    sv += __shfl_xor(sv, 2, 64);
                    sv += __shfl_xor(sv, 4, 64);
                    sv += __shfl_xor(sv, 8, 64);
                    if (lr == 0)
                        outb[ROWOFF + (o - ROWLO)] = sv + L->psum[lp][wn][o];
                }
            }
        }
    }
}

template<int A>
__device__ __forceinline__ void run_layers(
    LDSState* L, const bf16x8* w1p, const bf16x8* w2p, const bf16x8* w3p,
    const float* b1, const float* b2, const float* b3,
    float* outb, int tid, int mt0)
{
    const int wn = (tid >> 7) & 1;
    layer_core< 40,  50, 1, 100,   0, XB_STR, A>(L, w1p, b1,
        &L->xb[wn][0][0], &L->xf[wn][0][0], 0, 0, outb, tid, mt0);
    layer_core<104, 130, 1, 100, 100, HS_STR, A>(L, w2p, b2,
        &L->hs[0][wn][0][0], &L->xf[wn][0][0], 1, 1, outb, tid, mt0);
    layer_core<104, 130, 0,   0, 200, HS_STR, A>(L, w3p, b3,
        &L->hs[1][wn][0][0], &L->xf[wn][0][0], 0, 0, outb, tid, mt0);
}

__global__ __launch_bounds__(512, 2)
void fused_mfma(const float* __restrict__ x,
                const bf16x8* __restrict__ wpk,
                const float* __restrict__ b1, const float* __restrict__ b2,
                const float* __restrict__ b3, float* __restrict__ out) {
    __shared__ LDSState L;
    const int tid = threadIdx.x;
    const int bi  = blockIdx.x;

    // stage x (2 b's): fp32 -> xf (f32) and xb (bf16), transposed to [d][m]
    const float* xg = x + (size_t)(2 * bi) * 2560;
    for (int i = tid; i < 5120; i += 512) {
        int bb = (i >= 2560) ? 1 : 0;
        int r  = i - bb * 2560;
        int m = r >> 6, d = r & 63;
        float v = xg[(size_t)bb * 2560 + r];
        L.xf[bb][d][m] = v;
        L.xb[bb][d][m] = __float2bfloat16(v);
    }
    // zero-pad hs cols 100..107 (read range touches 96..103 for layers 2/3)
    for (int i = tid; i < 2 * 2 * 64 * 8; i += 512) {
        int c  = i & 7;
        int dd = (i >> 3) & 63;
        int bbp = i >> 9;                     // pp*2 + bb
        L.hs[bbp >> 1][bbp & 1][dd][100 + c] = __float2bfloat16(0.f);
    }
    __syncthreads();

    const int wn = (tid >> 7) & 1;
    float* outb = out + (size_t)(2 * bi + wn) * 400;

    const bf16x8* w1p = wpk;              // 13*50*64  = 41600 frags
    const bf16x8* w2p = wpk + 41600;      // 13*130*64 = 108160
    const bf16x8* w3p = wpk + 149760;

    if ((tid >> 8) == 0)
        run_layers<7>(&L, w1p, w2p, w3p, b1, b2, b3, outb, tid, 0);
    else
        run_layers<6>(&L, w1p, w2p, w3p, b1, b2, b3, outb, tid, 7);
}

// ---------------------------------------------------------------------------
// Prepass: repack W fp32 -> bf16 frag-contiguous with n padded to NPAD.
// Frag c = one lane's bf16x8 at layerbase + (mt*NK + s)*64 + lane holding
// W'[16mt + (lane&15), k0 .. k0+7], k0 = 32s + 8*(lane>>4);
// kk -> (m = kk/NPAD, n = kk%NPAD); value = W[row, m*DIV + n] if n<DIV and
// row<200, else 0. No 8-group straddles since NPAD % 8 == 0.
// ---------------------------------------------------------------------------
__global__ void convert_pack(const float* __restrict__ w1, const float* __restrict__ w2,
                             const float* __restrict__ w3, uint4* __restrict__ outp) {
    int c = blockIdx.x * 256 + threadIdx.x;
    if (c >= 257920) return;
    const float* src; int NK, DIV, NPAD, base;
    if (c < 41600)       { src = w1; NK = 50;  DIV = 40;  NPAD = 40;  base = c; }
    else if (c < 149760) { src = w2; NK = 130; DIV = 100; NPAD = 104; base = c - 41600; }
    else                 { src = w3; NK = 130; DIV = 100; NPAD = 104; base = c - 149760; }
    const int lane = base & 63;
    const int t    = base >> 6;
    const int mt   = t / NK;
    const int s    = t - mt * NK;
    const int row  = 16 * mt + (lane & 15);
    const int k0   = 32 * s + 8 * (lane >> 4);
    const int m    = k0 / NPAD;
    const int n0   = k0 - m * NPAD;
    uint o[4];
    if (row < 200) {
        const float* p = src + (size_t)row * (40 * DIV) + m * DIV + n0;
        #pragma unroll
        for (int j = 0; j < 4; ++j) {
            float flo = (n0 + 2 * j     < DIV) ? p[2 * j]     : 0.f;
            float fhi = (n0 + 2 * j + 1 < DIV) ? p[2 * j + 1] : 0.f;
            __hip_bfloat16 lo = __float2bfloat16(flo);
            __hip_bfloat16 hi = __float2bfloat16(fhi);
            o[j] = (uint)__builtin_bit_cast(unsigned short, lo)
                 | ((uint)__builtin_bit_cast(unsigned short, hi) << 16);
        }
    } else {
        #pragma unroll
        for (int j = 0; j < 4; ++j) o[j] = 0u;
    }
    uint4 v; v.x = o[0]; v.y = o[1]; v.z = o[2]; v.w = o[3];
    outp[c] = v;
}

// ---------------------------------------------------------------------------
// Fallback (fp32 VALU kernel) if ws too small.
// ---------------------------------------------------------------------------
__global__ __launch_bounds__(512, 1)
void fused_bilinear_kernel(const float* __restrict__ x,
                           const float* __restrict__ w1, const float* __restrict__ b1,
                           const float* __restrict__ w2, const float* __restrict__ b2,
                           const float* __restrict__ w3, const float* __restrict__ b3,
                           float* __restrict__ out) {
    const int b   = blockIdx.x;
    const int tid = threadIdx.x;
    const int d   = tid & 63;
    const int wv  = tid >> 6;

    __shared__ float xs[40][64];
    __shared__ float hs[100][64];

    const float* xb = x + (size_t)b * 40 * 64;
    for (int i = tid; i < 40 * 64; i += 512) ((float*)xs)[i] = xb[i];
    __syncthreads();

    float xr[40];
    #pragma unroll
    for (int m = 0; m < 40; ++m) xr[m] = xs[m][d];
    float hr[100];
    const int o0 = __builtin_amdgcn_readfirstlane(wv * 25);

    for (int oi = 0; oi < 25; ++oi) {
        const int o = o0 + oi;
        const float* __restrict__ wrow = w1 + (size_t)o * 1600;
        float s = b1[o];
        for (int m = 0; m < 40; ++m) {
            const float* __restrict__ wm = wrow + m * 40;
            float a0 = 0.f, a1 = 0.f, a2 = 0.f, a3 = 0.f;
            #pragma unroll
            for (int n = 0; n < 40; n += 4) {
                a0 = fmaf(wm[n + 0], xr[n + 0], a0);
                a1 = fmaf(wm[n + 1], xr[n + 1], a1);
                a2 = fmaf(wm[n + 2], xr[n + 2], a2);
                a3 = fmaf(wm[n + 3], xr[n + 3], a3);
            }
            s = fmaf(xs[m][d], (a0 + a1) + (a2 + a3), s);
        }
        s = fmaxf(s, 0.f);
        if (o < 100) hs[o][d] = s;
        else {
            float r = s;
            #pragma unroll
            for (int off = 32; off > 0; off >>= 1) r += __shfl_xor(r, off, 64);
            if (d == 0) out[(size_t)b * 400 + (o - 100)] = r;
        }
    }
    __syncthreads();
    #pragma unroll
    for (int n = 0; n < 100; ++n) hr[n] = hs[n][d];
    __syncthreads();

    for (int oi = 0; oi < 25; ++oi) {
        const int o = o0 + oi;
        const float* __restrict__ wrow = w2 + (size_t)o * 4000;
        float s = b2[o];
        for (int m = 0; m < 40; ++m) {
            const float* __restrict__ wm = wrow + m * 100;
            float a0 = 0.f, a1 = 0.f, a2 = 0.f, a3 = 0.f;
            #pragma unroll
            for (int n = 0; n < 100; n += 4) {
                a0 = fmaf(wm[n + 0], hr[n + 0], a0);
                a1 = fmaf(wm[n + 1], hr[n + 1], a1);
                a2 = fmaf(wm[n + 2], hr[n + 2], a2);
                a3 = fmaf(wm[n + 3], hr[n + 3], a3);
            }
            s = fmaf(xs[m][d], (a0 + a1) + (a2 + a3), s);
        }
        s = fmaxf(s, 0.f);
        if (o < 100) hs[o][d] = s;
        else {
            float r = s;
            #pragma unroll
            for (int off = 32; off > 0; off >>= 1) r += __shfl_xor(r, off, 64);
            if (d == 0) out[(size_t)b * 400 + 100 + (o - 100)] = r;
        }
    }
    __syncthreads();
    #pragma unroll
    for (int n = 0; n < 100; ++n) hr[n] = hs[n][d];

    for (int oi = 0; oi < 25; ++oi) {
        const int o = o0 + oi;
        const float* __restrict__ wrow = w3 + (size_t)o * 4000;
        float s = b3[o];
        for (int m = 0; m < 40; ++m) {
            const float* __restrict__ wm = wrow + m * 100;
            float a0 = 0.f, a1 = 0.f, a2 = 0.f, a3 = 0.f;
            #pragma unroll
            for (int n = 0; n < 100; n += 4) {
                a0 = fmaf(wm[n + 0], hr[n + 0], a0);
                a1 = fmaf(wm[n + 1], hr[n + 1], a1);
                a2 = fmaf(wm[n + 2], hr[n + 2], a2);
                a3 = fmaf(wm[n + 3], hr[n + 3], a3);
            }
            s = fmaf(xs[m][d], (a0 + a1) + (a2 + a3), s);
        }
        s = fmaxf(s, 0.f);
        float r = s;
        #pragma unroll
        for (int off = 32; off > 0; off >>= 1) r += __shfl_xor(r, off, 64);
        if (d == 0) out[(size_t)b * 400 + 200 + o] = r;
    }
}

extern "C" void kernel_launch(void* const* d_in, const int* in_sizes, int n_in,
                              void* d_out, int out_size, void* d_ws, size_t ws_size,
                              hipStream_t stream) {
    const float* x  = (const float*)d_in[0];
    const float* w1 = (const float*)d_in[1];
    const float* b1 = (const float*)d_in[2];
    const float* w2 = (const float*)d_in[3];
    const float* b2 = (const float*)d_in[4];
    const float* w3 = (const float*)d_in[5];
    const float* b3 = (const float*)d_in[6];
    float* out = (float*)d_out;

    if (ws_size >= 257920u * 16u) {
        uint4* wp = (uint4*)d_ws;
        convert_pack<<<dim3(1008), dim3(256), 0, stream>>>(w1, w2, w3, wp);
        fused_mfma<<<dim3(256), dim3(512), 0, stream>>>(
            x, (const bf16x8*)wp, b1, b2, b3, out);
    } else {
        fused_bilinear_kernel<<<dim3(512), dim3(512), 0, stream>>>(
            x, w1, b1, w2, b2, w3, b3, out);
    }
}

// Round 7
// 195.584 us; speedup vs baseline: 1.0829x; 1.0829x over previous
//
#include <hip/hip_runtime.h>
#include <hip/hip_bf16.h>

// ============================================================================
// B=512, M=40, D=64. Three bilinear layers (200 outputs each):
//   out[o,d] = relu(bias[o] + sum_c W[o,c]*U[c,d]), U[(m,n),d] = x[m,d]*h[n,d]
// Per b: GEMM C[208,64] = W[208,K] x U[K,64] bf16, K=1600/4000/4000.
// Block = 2 b's (N=128 cols), grid 256, 1024 threads = 16 waves (4/SIMD):
//   wv = tid>>6; gm = wv>>2 (m-tiles 4/3/3/3), wn = (wv>>1)&1 (batch),
//   nh = wv&1 (32-col half). Shared U-build in LDS (each wave builds 1 uint
//   = 2 k-slots per kstep per batch), XOR position perm (R5-verified):
//   logical uint u at dword pos 2*((u>>1)^((d>>1)&7)) + (u&1).
// W frag-contiguous from prepass; A-frags wave-private from global/L1 (fly
// across raw s_barriers, no vmcnt drain). 2-kstep phases, 4 slabs,
// lgkmcnt(0)+s_barrier only.
// ============================================================================

typedef float f32x4 __attribute__((ext_vector_type(4)));
typedef short bf16x8 __attribute__((ext_vector_type(8)));
typedef unsigned int uint;

#define XS_STR 44     // bf16; 88B rows
#define HS_STR 108    // bf16; 216B rows

struct LDSState {
    __hip_bfloat16 xs[2][64][XS_STR];     // [bb][d][m]         11264 B
    __hip_bfloat16 hs[2][2][64][HS_STR];  // [pp][bb][d][n]     55296 B
    uint U[4][2][64][16];                 // [slab][bb][d][pos] 32768 B
    float psum[2][2][208];                // [lp][bb][o]         6656 B
};

static __device__ __forceinline__ float bflo(uint u) {
    uint v = u << 16; return __builtin_bit_cast(float, v);
}
static __device__ __forceinline__ float bfhi(uint u) {
    uint v = u & 0xffff0000u; return __builtin_bit_cast(float, v);
}
static __device__ __forceinline__ uint pk_bf16(float a, float b) {
    uint r; asm("v_cvt_pk_bf16_f32 %0, %1, %2" : "=v"(r) : "v"(a), "v"(b));
    return r;
}

#define PHASE_BAR() do {                                   \
    asm volatile("s_waitcnt lgkmcnt(0)" ::: "memory");     \
    __builtin_amdgcn_sched_barrier(0);                     \
    __builtin_amdgcn_s_barrier();                          \
    __builtin_amdgcn_sched_barrier(0);                     \
} while (0)

template<int DIV, int NK, int HASH, int ROWLO, int ROWOFF, int HSTRIDE, int A>
__device__ __forceinline__ void layer_core(
    LDSState* L, const bf16x8* __restrict__ wpk, const float* __restrict__ bias,
    const __hip_bfloat16* __restrict__ h0, const __hip_bfloat16* __restrict__ h1,
    int dstpp, int lp, float* __restrict__ outb, int tid, int mt0)
{
    const int lane = tid & 63;
    const int wv = tid >> 6;              // 0..15
    const int wn = (wv >> 1) & 1, nh = wv & 1;
    const int q = lane >> 4, lr = lane & 15, d = lane;

    // ---- consume read bases (R5-verified perm) ----
    const int hdr = (lr >> 1) & 7;
    const uint* ub  = &L->U[0][0][0][0] + wn * 1024;
    const uint* roA = ub + (lr * 16 + 2 * ((2 * q) ^ hdr));
    const uint* roB = ub + (lr * 16 + 2 * ((2 * q + 1) ^ hdr));

    // ---- build write base: logical uint u = wv ----
    const int hdw = (d >> 1) & 7;
    uint* wb = &L->U[0][0][d][0] + 2 * ((wv >> 1) ^ hdw) + (wv & 1);

    const __hip_bfloat16* xb0 = &L->xs[0][d][0];
    const __hip_bfloat16* xb1 = &L->xs[1][d][0];
    const __hip_bfloat16* hb0 = h0 + d * HSTRIDE;
    const __hip_bfloat16* hb1 = h1 + d * HSTRIDE;

    f32x4 acc[A][2];
    #pragma unroll
    for (int mi = 0; mi < A; ++mi) {
        acc[mi][0] = {0.f, 0.f, 0.f, 0.f};
        acc[mi][1] = {0.f, 0.f, 0.f, 0.f};
    }

    // build state: kstep bk covers k-slots 2wv,2wv+1 -> c0 = 32*bk + 2*wv
    int bm = 0, bn = 2 * wv, bk = 0;      // 2wv < 32 <= DIV
    auto build = [&](int slab_dw) {
        if (bk < NK) {
            float xf0 = __bfloat162float(xb0[bm]);
            float xf1 = __bfloat162float(xb1[bm]);
            uint ha = *(const uint*)(hb0 + bn);
            uint hc = *(const uint*)(hb1 + bn);
            wb[slab_dw]        = pk_bf16(xf0 * bflo(ha), xf0 * bfhi(ha));
            wb[slab_dw + 1024] = pk_bf16(xf1 * bflo(hc), xf1 * bfhi(hc));
            bn += 32;
            if (bn >= DIV) { bn -= DIV; ++bm; }
            ++bk;
        }
    };

    auto consume = [&](int slab_dw, bf16x8* f) {
        bf16x8 bv[2];
        #pragma unroll
        for (int j = 0; j < 2; ++j) {
            const int nj = 2 * nh + j;
            union { uint2 u2[2]; bf16x8 v; } t;
            t.u2[0] = *(const uint2*)(roA + slab_dw + nj * 256);
            t.u2[1] = *(const uint2*)(roB + slab_dw + nj * 256);
            bv[j] = t.v;
        }
        #pragma unroll
        for (int mi = 0; mi < A; ++mi) {
            acc[mi][0] = __builtin_amdgcn_mfma_f32_16x16x32_bf16(
                f[mi], bv[0], acc[mi][0], 0, 0, 0);
            acc[mi][1] = __builtin_amdgcn_mfma_f32_16x16x32_bf16(
                f[mi], bv[1], acc[mi][1], 0, 0, 0);
        }
    };

    const bf16x8* pw = wpk + (size_t)mt0 * NK * 64 + lane;
    bf16x8 fA[A], fB[A];
    #pragma unroll
    for (int mi = 0; mi < A; ++mi) {
        fA[mi] = pw[(size_t)mi * NK * 64];
        fB[mi] = pw[(size_t)mi * NK * 64 + 64];
    }
    build(0);            // kstep 0 -> slab 0
    build(2048);         // kstep 1 -> slab 1
    __syncthreads();

    #pragma unroll 1
    for (int s = 0; s + 2 <= NK; s += 2) {
        const int sd0 = (s & 3) * 2048;
        const int sd1 = ((s + 1) & 3) * 2048;
        const int sd2 = ((s + 2) & 3) * 2048;
        const int sd3 = ((s + 3) & 3) * 2048;
        consume(sd0, fA);
        if (s + 2 < NK) {
            #pragma unroll
            for (int mi = 0; mi < A; ++mi)
                fA[mi] = pw[(size_t)mi * NK * 64 + (size_t)(s + 2) * 64];
        }
        consume(sd1, fB);
        if (s + 3 < NK) {
            #pragma unroll
            for (int mi = 0; mi < A; ++mi)
                fB[mi] = pw[(size_t)mi * NK * 64 + (size_t)(s + 3) * 64];
        }
        build(sd2);      // writes slabs (s+2)&3, (s+3)&3 (disjoint from reads)
        build(sd3);
        PHASE_BAR();
    }
    if (NK & 1) consume(0, fA);   // kstep NK-1, slab (NK-1)&3 == 0 for NK=125

    // ---- epilogue: C/D layout row = 4q+reg, col = lr (m89-verified) ----
    const int d0 = 32 * nh + lr, d1 = d0 + 16;
    #pragma unroll
    for (int mi = 0; mi < A; ++mi) {
        const int ob = 16 * (mt0 + mi) + 4 * q;
        #pragma unroll
        for (int reg = 0; reg < 4; ++reg) {
            const int o = ob + reg;
            if (o < 200) {
                const float bs = bias[o];
                float r0 = fmaxf(acc[mi][0][reg] + bs, 0.f);
                float r1 = fmaxf(acc[mi][1][reg] + bs, 0.f);
                if (HASH && o < 100) {
                    L->hs[dstpp][wn][d0][o] = __float2bfloat16(r0);
                    L->hs[dstpp][wn][d1][o] = __float2bfloat16(r1);
                }
                if (nh == 0 && o >= ROWLO) {
                    float sv = r0 + r1;
                    sv += __shfl_xor(sv, 1, 64);
                    sv += __shfl_xor(sv, 2, 64);
                    sv += __shfl_xor(sv, 4, 64);
                    sv += __shfl_xor(sv, 8, 64);
                    if (lr == 0) L->psum[lp][wn][o] = sv;
                }
            }
        }
    }
    __syncthreads();
    if (nh == 1) {
        #pragma unroll
        for (int mi = 0; mi < A; ++mi) {
            const int ob = 16 * (mt0 + mi) + 4 * q;
            #pragma unroll
            for (int reg = 0; reg < 4; ++reg) {
                const int o = ob + reg;
                if (o < 200 && o >= ROWLO) {
                    const float bs = bias[o];
                    float r0 = fmaxf(acc[mi][0][reg] + bs, 0.f);
                    float r1 = fmaxf(acc[mi][1][reg] + bs, 0.f);
                    float sv = r0 + r1;
                    sv += __shfl_xor(sv, 1, 64);
                    sv += __shfl_xor(sv, 2, 64);
                    sv += __shfl_xor(sv, 4, 64);
                    sv += __shfl_xor(sv, 8, 64);
                    if (lr == 0)
                        outb[ROWOFF + (o - ROWLO)] = sv + L->psum[lp][wn][o];
                }
            }
        }
    }
}

template<int A>
__device__ __forceinline__ void run_layers(
    LDSState* L, const bf16x8* w1p, const bf16x8* w2p, const bf16x8* w3p,
    const float* b1, const float* b2, const float* b3,
    float* outb, int tid, int mt0)
{
    layer_core< 40,  50, 1, 100,   0, XS_STR, A>(L, w1p, b1,
        &L->xs[0][0][0], &L->xs[1][0][0], 0, 0, outb, tid, mt0);
    layer_core<100, 125, 1, 100, 100, HS_STR, A>(L, w2p, b2,
        &L->hs[0][0][0][0], &L->hs[0][1][0][0], 1, 1, outb, tid, mt0);
    layer_core<100, 125, 0,   0, 200, HS_STR, A>(L, w3p, b3,
        &L->hs[1][0][0][0], &L->hs[1][1][0][0], 0, 0, outb, tid, mt0);
}

__global__ __launch_bounds__(1024)
void fused_mfma(const float* __restrict__ x,
                const bf16x8* __restrict__ wpk,
                const float* __restrict__ b1, const float* __restrict__ b2,
                const float* __restrict__ b3, float* __restrict__ out) {
    __shared__ LDSState L;
    const int tid = threadIdx.x;
    const int bi  = blockIdx.x;

    // stage x (2 b's), fp32 -> bf16, transposed to [d][m]
    const float* xg = x + (size_t)(2 * bi) * 2560;
    for (int i = tid; i < 5120; i += 1024) {
        int bb = (i >= 2560) ? 1 : 0;
        int r  = i - bb * 2560;
        L.xs[bb][r & 63][r >> 6] = __float2bfloat16(xg[(size_t)bb * 2560 + r]);
    }
    __syncthreads();

    const int wn = (tid >> 7) & 1;
    float* outb = out + (size_t)(2 * bi + wn) * 400;

    const bf16x8* w1p = wpk;              // 13*50*64  = 41600 frags
    const bf16x8* w2p = wpk + 41600;      // 13*125*64 = 104000
    const bf16x8* w3p = wpk + 145600;

    const int gm = tid >> 8;              // 0..3
    if (gm == 0)
        run_layers<4>(&L, w1p, w2p, w3p, b1, b2, b3, outb, tid, 0);
    else
        run_layers<3>(&L, w1p, w2p, w3p, b1, b2, b3, outb, tid, 4 + 3 * (gm - 1));
}

// ---------------------------------------------------------------------------
// Prepass: repack W fp32 -> bf16 frag-contiguous. Element c = one lane's
// bf16x8: c = layerbase + (mt*NK + s)*64 + lane, holding
// W[16*mt + (lane&15), 32*s + 8*(lane>>4) .. +8]  (rows >= 200 zero).
// ---------------------------------------------------------------------------
__global__ void convert_pack(const float* __restrict__ w1, const float* __restrict__ w2,
                             const float* __restrict__ w3, uint4* __restrict__ outp) {
    int c = blockIdx.x * 256 + threadIdx.x;
    if (c >= 249600) return;
    const float* src; int K, base;
    if (c < 41600)       { src = w1; K = 1600; base = c; }
    else if (c < 145600) { src = w2; K = 4000; base = c - 41600; }
    else                 { src = w3; K = 4000; base = c - 145600; }
    const int NS   = K / 32;
    const int lane = base & 63;
    const int t    = base >> 6;
    const int mt   = t / NS;
    const int s    = t - mt * NS;
    const int row  = 16 * mt + (lane & 15);
    const int k0   = 32 * s + 8 * (lane >> 4);
    uint o[4];
    if (row < 200) {
        const float* p = src + (size_t)row * K + k0;
        #pragma unroll
        for (int j = 0; j < 4; ++j) {
            __hip_bfloat16 lo = __float2bfloat16(p[2 * j]);
            __hip_bfloat16 hi = __float2bfloat16(p[2 * j + 1]);
            o[j] = (uint)__builtin_bit_cast(unsigned short, lo)
                 | ((uint)__builtin_bit_cast(unsigned short, hi) << 16);
        }
    } else {
        #pragma unroll
        for (int j = 0; j < 4; ++j) o[j] = 0u;
    }
    uint4 v; v.x = o[0]; v.y = o[1]; v.z = o[2]; v.w = o[3];
    outp[c] = v;
}

// ---------------------------------------------------------------------------
// Fallback (fp32 VALU kernel) if ws too small.
// ---------------------------------------------------------------------------
__global__ __launch_bounds__(512, 1)
void fused_bilinear_kernel(const float* __restrict__ x,
                           const float* __restrict__ w1, const float* __restrict__ b1,
                           const float* __restrict__ w2, const float* __restrict__ b2,
                           const float* __restrict__ w3, const float* __restrict__ b3,
                           float* __restrict__ out) {
    const int b   = blockIdx.x;
    const int tid = threadIdx.x;
    const int d   = tid & 63;
    const int wv  = tid >> 6;

    __shared__ float xs[40][64];
    __shared__ float hs[100][64];

    const float* xb = x + (size_t)b * 40 * 64;
    for (int i = tid; i < 40 * 64; i += 512) ((float*)xs)[i] = xb[i];
    __syncthreads();

    float xr[40];
    #pragma unroll
    for (int m = 0; m < 40; ++m) xr[m] = xs[m][d];
    float hr[100];
    const int o0 = __builtin_amdgcn_readfirstlane(wv * 25);

    for (int oi = 0; oi < 25; ++oi) {
        const int o = o0 + oi;
        const float* __restrict__ wrow = w1 + (size_t)o * 1600;
        float s = b1[o];
        for (int m = 0; m < 40; ++m) {
            const float* __restrict__ wm = wrow + m * 40;
            float a0 = 0.f, a1 = 0.f, a2 = 0.f, a3 = 0.f;
            #pragma unroll
            for (int n = 0; n < 40; n += 4) {
                a0 = fmaf(wm[n + 0], xr[n + 0], a0);
                a1 = fmaf(wm[n + 1], xr[n + 1], a1);
                a2 = fmaf(wm[n + 2], xr[n + 2], a2);
                a3 = fmaf(wm[n + 3], xr[n + 3], a3);
            }
            s = fmaf(xs[m][d], (a0 + a1) + (a2 + a3), s);
        }
        s = fmaxf(s, 0.f);
        if (o < 100) hs[o][d] = s;
        else {
            float r = s;
            #pragma unroll
            for (int off = 32; off > 0; off >>= 1) r += __shfl_xor(r, off, 64);
            if (d == 0) out[(size_t)b * 400 + (o - 100)] = r;
        }
    }
    __syncthreads();
    #pragma unroll
    for (int n = 0; n < 100; ++n) hr[n] = hs[n][d];
    __syncthreads();

    for (int oi = 0; oi < 25; ++oi) {
        const int o = o0 + oi;
        const float* __restrict__ wrow = w2 + (size_t)o * 4000;
        float s = b2[o];
        for (int m = 0; m < 40; ++m) {
            const float* __restrict__ wm = wrow + m * 100;
            float a0 = 0.f, a1 = 0.f, a2 = 0.f, a3 = 0.f;
            #pragma unroll
            for (int n = 0; n < 100; n += 4) {
                a0 = fmaf(wm[n + 0], hr[n + 0], a0);
                a1 = fmaf(wm[n + 1], hr[n + 1], a1);
                a2 = fmaf(wm[n + 2], hr[n + 2], a2);
                a3 = fmaf(wm[n + 3], hr[n + 3], a3);
            }
            s = fmaf(xs[m][d], (a0 + a1) + (a2 + a3), s);
        }
        s = fmaxf(s, 0.f);
        if (o < 100) hs[o][d] = s;
        else {
            float r = s;
            #pragma unroll
            for (int off = 32; off > 0; off >>= 1) r += __shfl_xor(r, off, 64);
            if (d == 0) out[(size_t)b * 400 + 100 + (o - 100)] = r;
        }
    }
    __syncthreads();
    #pragma unroll
    for (int n = 0; n < 100; ++n) hr[n] = hs[n][d];

    for (int oi = 0; oi < 25; ++oi) {
        const int o = o0 + oi;
        const float* __restrict__ wrow = w3 + (size_t)o * 4000;
        float s = b3[o];
        for (int m = 0; m < 40; ++m) {
            const float* __restrict__ wm = wrow + m * 100;
            float a0 = 0.f, a1 = 0.f, a2 = 0.f, a3 = 0.f;
            #pragma unroll
            for (int n = 0; n < 100; n += 4) {
                a0 = fmaf(wm[n + 0], hr[n + 0], a0);
                a1 = fmaf(wm[n + 1], hr[n + 1], a1);
                a2 = fmaf(wm[n + 2], hr[n + 2], a2);
                a3 = fmaf(wm[n + 3], hr[n + 3], a3);
            }
            s = fmaf(xs[m][d], (a0 + a1) + (a2 + a3), s);
        }
        s = fmaxf(s, 0.f);
        float r = s;
        #pragma unroll
        for (int off = 32; off > 0; off >>= 1) r += __shfl_xor(r, off, 64);
        if (d == 0) out[(size_t)b * 400 + 200 + o] = r;
    }
}

extern "C" void kernel_launch(void* const* d_in, const int* in_sizes, int n_in,
                              void* d_out, int out_size, void* d_ws, size_t ws_size,
                              hipStream_t stream) {
    const float* x  = (const float*)d_in[0];
    const float* w1 = (const float*)d_in[1];
    const float* b1 = (const float*)d_in[2];
    const float* w2 = (const float*)d_in[3];
    const float* b2 = (const float*)d_in[4];
    const float* w3 = (const float*)d_in[5];
    const float* b3 = (const float*)d_in[6];
    float* out = (float*)d_out;

    if (ws_size >= 249600u * 16u) {
        uint4* wp = (uint4*)d_ws;
        convert_pack<<<dim3(975), dim3(256), 0, stream>>>(w1, w2, w3, wp);
        fused_mfma<<<dim3(256), dim3(1024), 0, stream>>>(
            x, (const bf16x8*)wp, b1, b2, b3, out);
    } else {
        fused_bilinear_kernel<<<dim3(512), dim3(512), 0, stream>>>(
            x, w1, b1, w2, b2, w3, b3, out);
    }
}

// Round 8
// 184.246 us; speedup vs baseline: 1.1496x; 1.0615x over previous
//
#include <hip/hip_runtime.h>
#include <hip/hip_bf16.h>

// ============================================================================
// B=512, M=40, D=64. Three bilinear layers (200 outputs each):
//   out[o,d] = relu(bias[o] + sum_c W[o,c]*U[c,d]), U[(m,n),d] = x[m,d]*h[n,d]
// Per b: GEMM C[208,64] = W[208,K] x U[K,64] bf16, K=1600/4000/4000.
// R8: block = ONE batch (N=64), 512 thr = 8 waves, grid 512 -> 2-3 independent
// blocks/CU (LDS ~50KB). Barrier drains of one block overlap compute of the
// others (m114). Inner structure = R5-verified: shared U-build in LDS with XOR
// position perm (logical uint u at dword 2*((u>>1)^((d>>1)&7)) + (u&1)),
// frag-contiguous W (prepass), 2-kstep phases, 4 slabs, raw s_barrier +
// lgkmcnt(0) only (A-frag global loads fly across barriers).
// Waves: wv=tid>>6; gm=wv>>1 (m-tiles 4/3/3/3 at mt0=0/4/7/10), nh=wv&1
// (cols 32nh..32nh+31 via nj in {2nh,2nh+1}).
// ============================================================================

typedef float f32x4 __attribute__((ext_vector_type(4)));
typedef short bf16x8 __attribute__((ext_vector_type(8)));
typedef unsigned int uint;

#define XS_STR 44     // bf16; 88B rows (8B-aligned, 22dw: 2-way banks)
#define HS_STR 108    // bf16; 216B rows (8B-aligned, 54dw)

struct LDSState {
    __hip_bfloat16 xs[64][44];      // [d][m]           5632 B
    __hip_bfloat16 hs[2][64][108];  // [pp][d][n]      27648 B
    uint U[4][64][16];              // [slab][d][pos]  16384 B
    float psum[304];                // layered regions  1216 B
};                                  // total ~50880 B -> 3 blocks/CU by LDS

static __device__ __forceinline__ float bflo(uint u) {
    uint v = u << 16; return __builtin_bit_cast(float, v);
}
static __device__ __forceinline__ float bfhi(uint u) {
    uint v = u & 0xffff0000u; return __builtin_bit_cast(float, v);
}
static __device__ __forceinline__ uint pk_bf16(float a, float b) {
    uint r; asm("v_cvt_pk_bf16_f32 %0, %1, %2" : "=v"(r) : "v"(a), "v"(b));
    return r;
}

#define PHASE_BAR() do {                                   \
    asm volatile("s_waitcnt lgkmcnt(0)" ::: "memory");     \
    __builtin_amdgcn_sched_barrier(0);                     \
    __builtin_amdgcn_s_barrier();                          \
    __builtin_amdgcn_sched_barrier(0);                     \
} while (0)

template<int DIV, int NK, int HASH, int ROWLO, int ROWOFF, int HSTRIDE, int A>
__device__ __forceinline__ void layer_core(
    LDSState* L, const bf16x8* __restrict__ wpk, const float* __restrict__ bias,
    const __hip_bfloat16* __restrict__ hbase,
    int dstpp, int psoff, float* __restrict__ outb, int tid, int mt0)
{
    const int lane = tid & 63;
    const int wv = tid >> 6;              // 0..7
    const int nh = wv & 1;
    const int q = lane >> 4, lr = lane & 15, d = lane;

    // ---- consume read bases (R5-verified perm) ----
    const int hdr = (lr >> 1) & 7;
    const uint* ub  = &L->U[0][0][0];
    const uint* roA = ub + (lr * 16 + 2 * ((2 * q) ^ hdr));
    const uint* roB = ub + (lr * 16 + 2 * ((2 * q + 1) ^ hdr));

    // ---- build write base: wave wv owns k-slots 4wv..4wv+3 (uints 2wv,2wv+1)
    const int hdw = (d >> 1) & 7;
    uint* wb = &L->U[0][d][0] + 2 * (wv ^ hdw);

    const __hip_bfloat16* xrow = &L->xs[d][0];
    const __hip_bfloat16* hrow = hbase + d * HSTRIDE;

    f32x4 acc[A][2];
    #pragma unroll
    for (int mi = 0; mi < A; ++mi) {
        acc[mi][0] = {0.f, 0.f, 0.f, 0.f};
        acc[mi][1] = {0.f, 0.f, 0.f, 0.f};
    }

    // build state: kstep bk covers slots c0 = 32*bk + 4*wv .. +3
    int bm = (4 * wv) / DIV;              // 0 (4wv < 32 <= DIV)
    int bn = 4 * wv;
    int bk = 0;
    auto build = [&](int slab_dw) {
        if (bk < NK) {
            float xf = __bfloat162float(xrow[bm]);
            uint2 ha = *(const uint2*)(hrow + bn);
            uint2 w;
            w.x = pk_bf16(xf * bflo(ha.x), xf * bfhi(ha.x));
            w.y = pk_bf16(xf * bflo(ha.y), xf * bfhi(ha.y));
            *(uint2*)(wb + slab_dw) = w;
            bn += 32;
            if (bn >= DIV) { bn -= DIV; ++bm; }
            ++bk;
        }
    };

    auto consume = [&](int slab_dw, bf16x8* f) {
        bf16x8 bv[2];
        #pragma unroll
        for (int j = 0; j < 2; ++j) {
            const int nj = 2 * nh + j;
            union { uint2 u2[2]; bf16x8 v; } t;
            t.u2[0] = *(const uint2*)(roA + slab_dw + nj * 256);
            t.u2[1] = *(const uint2*)(roB + slab_dw + nj * 256);
            bv[j] = t.v;
        }
        #pragma unroll
        for (int mi = 0; mi < A; ++mi) {
            acc[mi][0] = __builtin_amdgcn_mfma_f32_16x16x32_bf16(
                f[mi], bv[0], acc[mi][0], 0, 0, 0);
            acc[mi][1] = __builtin_amdgcn_mfma_f32_16x16x32_bf16(
                f[mi], bv[1], acc[mi][1], 0, 0, 0);
        }
    };

    const bf16x8* pw = wpk + (size_t)mt0 * NK * 64 + lane;
    bf16x8 fA[A], fB[A];
    #pragma unroll
    for (int mi = 0; mi < A; ++mi) {
        fA[mi] = pw[(size_t)mi * NK * 64];
        fB[mi] = pw[(size_t)mi * NK * 64 + 64];
    }
    build(0);            // kstep 0 -> slab 0
    build(1024);         // kstep 1 -> slab 1
    __syncthreads();

    #pragma unroll 1
    for (int s = 0; s + 2 <= NK; s += 2) {
        const int sd0 = (s & 3) * 1024;
        const int sd1 = ((s + 1) & 3) * 1024;
        const int sd2 = ((s + 2) & 3) * 1024;
        const int sd3 = ((s + 3) & 3) * 1024;
        consume(sd0, fA);
        if (s + 2 < NK) {
            #pragma unroll
            for (int mi = 0; mi < A; ++mi)
                fA[mi] = pw[(size_t)mi * NK * 64 + (size_t)(s + 2) * 64];
        }
        consume(sd1, fB);
        if (s + 3 < NK) {
            #pragma unroll
            for (int mi = 0; mi < A; ++mi)
                fB[mi] = pw[(size_t)mi * NK * 64 + (size_t)(s + 3) * 64];
        }
        build(sd2);      // writes slabs (s+2)&3,(s+3)&3 (disjoint from reads)
        build(sd3);
        PHASE_BAR();
    }
    if (NK & 1) consume(0, fA);   // NK=125: kstep 124, slab 124&3 == 0

    // ---- epilogue: C/D layout row = 4q+reg, col = lr (m89-verified) ----
    // wave nh covers cols d0 = 32nh+lr (j=0) and d1 = d0+16 (j=1)
    const int d0 = 32 * nh + lr, d1 = d0 + 16;
    #pragma unroll
    for (int mi = 0; mi < A; ++mi) {
        const int ob = 16 * (mt0 + mi) + 4 * q;
        #pragma unroll
        for (int reg = 0; reg < 4; ++reg) {
            const int o = ob + reg;
            if (o < 200) {
                const float bs = bias[o];
                float r0 = fmaxf(acc[mi][0][reg] + bs, 0.f);
                float r1 = fmaxf(acc[mi][1][reg] + bs, 0.f);
                if (HASH && o < 100) {
                    L->hs[dstpp][d0][o] = __float2bfloat16(r0);
                    L->hs[dstpp][d1][o] = __float2bfloat16(r1);
                }
                if (nh == 0 && o >= ROWLO) {
                    float sv = r0 + r1;
                    sv += __shfl_xor(sv, 1, 64);
                    sv += __shfl_xor(sv, 2, 64);
                    sv += __shfl_xor(sv, 4, 64);
                    sv += __shfl_xor(sv, 8, 64);
                    if (lr == 0) L->psum[psoff + (o - ROWLO)] = sv;
                }
            }
        }
    }
    __syncthreads();
    if (nh == 1) {
        #pragma unroll
        for (int mi = 0; mi < A; ++mi) {
            const int ob = 16 * (mt0 + mi) + 4 * q;
            #pragma unroll
            for (int reg = 0; reg < 4; ++reg) {
                const int o = ob + reg;
                if (o < 200 && o >= ROWLO) {
                    const float bs = bias[o];
                    float r0 = fmaxf(acc[mi][0][reg] + bs, 0.f);
                    float r1 = fmaxf(acc[mi][1][reg] + bs, 0.f);
                    float sv = r0 + r1;
                    sv += __shfl_xor(sv, 1, 64);
                    sv += __shfl_xor(sv, 2, 64);
                    sv += __shfl_xor(sv, 4, 64);
                    sv += __shfl_xor(sv, 8, 64);
                    if (lr == 0)
                        outb[ROWOFF + (o - ROWLO)] =
                            sv + L->psum[psoff + (o - ROWLO)];
                }
            }
        }
    }
}

template<int A>
__device__ __forceinline__ void run_layers(
    LDSState* L, const bf16x8* w1p, const bf16x8* w2p, const bf16x8* w3p,
    const float* b1, const float* b2, const float* b3,
    float* outb, int tid, int mt0)
{
    layer_core< 40,  50, 1, 100,   0, XS_STR, A>(L, w1p, b1,
        &L->xs[0][0],    0,   0, outb, tid, mt0);
    layer_core<100, 125, 1, 100, 100, HS_STR, A>(L, w2p, b2,
        &L->hs[0][0][0], 1, 200, outb, tid, mt0);
    layer_core<100, 125, 0,   0, 200, HS_STR, A>(L, w3p, b3,
        &L->hs[1][0][0], 0,   0, outb, tid, mt0);
}

__global__ __launch_bounds__(512, 4)
void fused_mfma(const float* __restrict__ x,
                const bf16x8* __restrict__ wpk,
                const float* __restrict__ b1, const float* __restrict__ b2,
                const float* __restrict__ b3, float* __restrict__ out) {
    __shared__ LDSState L;
    const int tid = threadIdx.x;
    const int bi  = blockIdx.x;           // one batch per block

    // stage x (1 b), fp32 -> bf16, transposed to [d][m]
    const float* xg = x + (size_t)bi * 2560;
    for (int i = tid; i < 2560; i += 512) {
        L.xs[i & 63][i >> 6] = __float2bfloat16(xg[i]);
    }
    __syncthreads();

    float* outb = out + (size_t)bi * 400;

    const bf16x8* w1p = wpk;              // 13*50*64  = 41600 frags
    const bf16x8* w2p = wpk + 41600;      // 13*125*64 = 104000
    const bf16x8* w3p = wpk + 145600;

    const int gm = (tid >> 7);            // 0..3 (wave pairs)
    if (gm == 0)
        run_layers<4>(&L, w1p, w2p, w3p, b1, b2, b3, outb, tid, 0);
    else
        run_layers<3>(&L, w1p, w2p, w3p, b1, b2, b3, outb, tid, 4 + 3 * (gm - 1));
}

// ---------------------------------------------------------------------------
// Prepass: repack W fp32 -> bf16 frag-contiguous. Element c = one lane's
// bf16x8: c = layerbase + (mt*NK + s)*64 + lane, holding
// W[16*mt + (lane&15), 32*s + 8*(lane>>4) .. +8]  (rows >= 200 zero).
// ---------------------------------------------------------------------------
__global__ void convert_pack(const float* __restrict__ w1, const float* __restrict__ w2,
                             const float* __restrict__ w3, uint4* __restrict__ outp) {
    int c = blockIdx.x * 256 + threadIdx.x;
    if (c >= 249600) return;
    const float* src; int K, base;
    if (c < 41600)       { src = w1; K = 1600; base = c; }
    else if (c < 145600) { src = w2; K = 4000; base = c - 41600; }
    else                 { src = w3; K = 4000; base = c - 145600; }
    const int NS   = K / 32;
    const int lane = base & 63;
    const int t    = base >> 6;
    const int mt   = t / NS;
    const int s    = t - mt * NS;
    const int row  = 16 * mt + (lane & 15);
    const int k0   = 32 * s + 8 * (lane >> 4);
    uint o[4];
    if (row < 200) {
        const float* p = src + (size_t)row * K + k0;
        #pragma unroll
        for (int j = 0; j < 4; ++j) {
            __hip_bfloat16 lo = __float2bfloat16(p[2 * j]);
            __hip_bfloat16 hi = __float2bfloat16(p[2 * j + 1]);
            o[j] = (uint)__builtin_bit_cast(unsigned short, lo)
                 | ((uint)__builtin_bit_cast(unsigned short, hi) << 16);
        }
    } else {
        #pragma unroll
        for (int j = 0; j < 4; ++j) o[j] = 0u;
    }
    uint4 v; v.x = o[0]; v.y = o[1]; v.z = o[2]; v.w = o[3];
    outp[c] = v;
}

// ---------------------------------------------------------------------------
// Fallback (fp32 VALU kernel) if ws too small.
// ---------------------------------------------------------------------------
__global__ __launch_bounds__(512, 1)
void fused_bilinear_kernel(const float* __restrict__ x,
                           const float* __restrict__ w1, const float* __restrict__ b1,
                           const float* __restrict__ w2, const float* __restrict__ b2,
                           const float* __restrict__ w3, const float* __restrict__ b3,
                           float* __restrict__ out) {
    const int b   = blockIdx.x;
    const int tid = threadIdx.x;
    const int d   = tid & 63;
    const int wv  = tid >> 6;

    __shared__ float xs[40][64];
    __shared__ float hs[100][64];

    const float* xb = x + (size_t)b * 40 * 64;
    for (int i = tid; i < 40 * 64; i += 512) ((float*)xs)[i] = xb[i];
    __syncthreads();

    float xr[40];
    #pragma unroll
    for (int m = 0; m < 40; ++m) xr[m] = xs[m][d];
    float hr[100];
    const int o0 = __builtin_amdgcn_readfirstlane(wv * 25);

    for (int oi = 0; oi < 25; ++oi) {
        const int o = o0 + oi;
        const float* __restrict__ wrow = w1 + (size_t)o * 1600;
        float s = b1[o];
        for (int m = 0; m < 40; ++m) {
            const float* __restrict__ wm = wrow + m * 40;
            float a0 = 0.f, a1 = 0.f, a2 = 0.f, a3 = 0.f;
            #pragma unroll
            for (int n = 0; n < 40; n += 4) {
                a0 = fmaf(wm[n + 0], xr[n + 0], a0);
                a1 = fmaf(wm[n + 1], xr[n + 1], a1);
                a2 = fmaf(wm[n + 2], xr[n + 2], a2);
                a3 = fmaf(wm[n + 3], xr[n + 3], a3);
            }
            s = fmaf(xs[m][d], (a0 + a1) + (a2 + a3), s);
        }
        s = fmaxf(s, 0.f);
        if (o < 100) hs[o][d] = s;
        else {
            float r = s;
            #pragma unroll
            for (int off = 32; off > 0; off >>= 1) r += __shfl_xor(r, off, 64);
            if (d == 0) out[(size_t)b * 400 + (o - 100)] = r;
        }
    }
    __syncthreads();
    #pragma unroll
    for (int n = 0; n < 100; ++n) hr[n] = hs[n][d];
    __syncthreads();

    for (int oi = 0; oi < 25; ++oi) {
        const int o = o0 + oi;
        const float* __restrict__ wrow = w2 + (size_t)o * 4000;
        float s = b2[o];
        for (int m = 0; m < 40; ++m) {
            const float* __restrict__ wm = wrow + m * 100;
            float a0 = 0.f, a1 = 0.f, a2 = 0.f, a3 = 0.f;
            #pragma unroll
            for (int n = 0; n < 100; n += 4) {
                a0 = fmaf(wm[n + 0], hr[n + 0], a0);
                a1 = fmaf(wm[n + 1], hr[n + 1], a1);
                a2 = fmaf(wm[n + 2], hr[n + 2], a2);
                a3 = fmaf(wm[n + 3], hr[n + 3], a3);
            }
            s = fmaf(xs[m][d], (a0 + a1) + (a2 + a3), s);
        }
        s = fmaxf(s, 0.f);
        if (o < 100) hs[o][d] = s;
        else {
            float r = s;
            #pragma unroll
            for (int off = 32; off > 0; off >>= 1) r += __shfl_xor(r, off, 64);
            if (d == 0) out[(size_t)b * 400 + 100 + (o - 100)] = r;
        }
    }
    __syncthreads();
    #pragma unroll
    for (int n = 0; n < 100; ++n) hr[n] = hs[n][d];

    for (int oi = 0; oi < 25; ++oi) {
        const int o = o0 + oi;
        const float* __restrict__ wrow = w3 + (size_t)o * 4000;
        float s = b3[o];
        for (int m = 0; m < 40; ++m) {
            const float* __restrict__ wm = wrow + m * 100;
            float a0 = 0.f, a1 = 0.f, a2 = 0.f, a3 = 0.f;
            #pragma unroll
            for (int n = 0; n < 100; n += 4) {
                a0 = fmaf(wm[n + 0], hr[n + 0], a0);
                a1 = fmaf(wm[n + 1], hr[n + 1], a1);
                a2 = fmaf(wm[n + 2], hr[n + 2], a2);
                a3 = fmaf(wm[n + 3], hr[n + 3], a3);
            }
            s = fmaf(xs[m][d], (a0 + a1) + (a2 + a3), s);
        }
        s = fmaxf(s, 0.f);
        float r = s;
        #pragma unroll
        for (int off = 32; off > 0; off >>= 1) r += __shfl_xor(r, off, 64);
        if (d == 0) out[(size_t)b * 400 + 200 + o] = r;
    }
}

extern "C" void kernel_launch(void* const* d_in, const int* in_sizes, int n_in,
                              void* d_out, int out_size, void* d_ws, size_t ws_size,
                              hipStream_t stream) {
    const float* x  = (const float*)d_in[0];
    const float* w1 = (const float*)d_in[1];
    const float* b1 = (const float*)d_in[2];
    const float* w2 = (const float*)d_in[3];
    const float* b2 = (const float*)d_in[4];
    const float* w3 = (const float*)d_in[5];
    const float* b3 = (const float*)d_in[6];
    float* out = (float*)d_out;

    if (ws_size >= 249600u * 16u) {
        uint4* wp = (uint4*)d_ws;
        convert_pack<<<dim3(975), dim3(256), 0, stream>>>(w1, w2, w3, wp);
        fused_mfma<<<dim3(512), dim3(512), 0, stream>>>(
            x, (const bf16x8*)wp, b1, b2, b3, out);
    } else {
        fused_bilinear_kernel<<<dim3(512), dim3(512), 0, stream>>>(
            x, w1, b1, w2, b2, w3, b3, out);
    }
}